// Round 12
// baseline (531.533 us; speedup 1.0000x reference)
//
#include <hip/hip_runtime.h>
#include <math.h>

// Problem constants
constexpr int kB    = 4;
constexpr int kNSEM = 12;
constexpr int kH    = 480;
constexpr int kW    = 640;
constexpr int kNPIX = kH * kW;           // 307200
constexpr int kNCH  = 16;                // rgb(3) + depth(1) + sem(12)
constexpr int kVR   = 100;
constexpr int kNZ   = 80;
constexpr int kZLO  = 13;                // agent window [13,25)
constexpr int kZHI  = 25;
constexpr int kNCELL  = kVR * kVR * kNZ; // 800000 floor-cells
constexpr int kNCHUNK = kNCELL / 256;    // 3125

// ---- per-batch ws layout (bytes) — total 5.0 MB/batch ----
constexpr size_t CNT_OFF  = 0;                                   // 800000 x u32
constexpr size_t IDX_OFF  = CNT_OFF + (size_t)kNCELL * 4;        // 307200 x u32 (pix<<12 | mask)
constexpr size_t PART_OFF = IDX_OFF + (size_t)kNPIX * 4;         // 3125 x u32 (pad 12544B)
constexpr size_t COL_OFF  = PART_OFF + 12544;                    // 14 x 10000 f32 column sums
constexpr size_t BSTRIDE  = COL_OFF + (size_t)14 * 10000 * 4;    // 5,001,344 B

// Block hipcc contraction of the weight product into the accumulate add
// (XLA's scatter is a separate HLO — its adds are separately rounded).
__device__ __forceinline__ float nofuse_f(float x) {
    asm volatile("" : "+v"(x));
    return x;
}

// XLA-jit canonical geometry (algebraic simplifier + LLVM fma contraction):
//  * divide-by-constant -> multiply-by-reciprocal (rcpF = 1/f32(F_CAM),
//    1/5 = 0.2f)
//  * consecutive const-mul folding: x*0.01f*2f*50f -> x*1.0f (0.02f*50f
//    rounds to EXACTLY 1.0f) -> elided; same for z (0.025f*40f -> 1.0f)
//  * add-const cancellation: -50+50 -> 0; -32+40 -> +8
//  * remaining mul+add pairs contracted to FMA
// Result:
//   p0 = fma(tx, rcpF, 250) * 0.2f
//   p1 = d * 0.2f
//   p2 = fma(fma(tz, rcpF, 88), 0.2f, 8)
__device__ __forceinline__ void geom_f(int xi, int zi, float d, float rcpF,
                                       float& p0, float& p1, float& p2) {
    float tx  = ((float)xi - 319.5f) * d;
    float tz  = (239.5f - (float)zi) * d;
    float x_w = fmaf(tx, rcpF, 250.0f);
    float z_w = fmaf(tz, rcpF, 88.0f);
    p0 = x_w * 0.2f;
    p1 = d   * 0.2f;
    p2 = fmaf(z_w, 0.2f, 8.0f);
}

// Floor-cell + sem mask; false if the floor cell is outside the grid (then all
// 8 corner weights are safe-zeroed in the reference — exact no-ops).
__device__ __forceinline__ bool cellmask(const float* __restrict__ ob, int pix,
                                         float rcpF, unsigned& cell,
                                         unsigned& mask, bool want_mask) {
    int zi = pix / kW, xi = pix - zi * kW;
    float d = ob[3 * kNPIX + pix];
    float p0, p1, p2;
    geom_f(xi, zi, d, rcpF, p0, p1, p2);
    int fx = (int)floorf(p0), fy = (int)floorf(p1), fz = (int)floorf(p2);
    if (fx < 0 || fx >= kVR || fy < 0 || fy >= kVR || fz < 0 || fz >= kNZ)
        return false;
    cell = ((unsigned)(fx * kVR + fy)) * (unsigned)kNZ + (unsigned)fz;
    mask = 0;
    if (want_mask) {
#pragma unroll
        for (int c = 0; c < kNSEM; ++c)
            if (ob[(4 + c) * kNPIX + pix] != 0.0f) mask |= (1u << c);
    }
    return true;
}

// K1: count pixels per floor cell.
__global__ __launch_bounds__(256) void build_kernel(
        const float* __restrict__ obs, char* __restrict__ ws,
        int b0, int nb, float rcpF) {
    int t = blockIdx.x * blockDim.x + threadIdx.x;
    if (t >= nb * kNPIX) return;
    int lb = t / kNPIX, pix = t - lb * kNPIX;
    const float* ob = obs + (size_t)(b0 + lb) * kNCH * kNPIX;
    unsigned cell, mask;
    if (cellmask(ob, pix, rcpF, cell, mask, false))
        atomicAdd((unsigned*)(ws + (size_t)lb * BSTRIDE + CNT_OFF) + cell, 1u);
}

// K2a: per 256-cell chunk — in-place chunk-exclusive scan; chunk total -> part.
__global__ __launch_bounds__(256) void scan_block_kernel(char* __restrict__ ws) {
    int blk = blockIdx.x, t = threadIdx.x;
    int lb = blk / kNCHUNK, chunk = blk - lb * kNCHUNK;
    char* base = ws + (size_t)lb * BSTRIDE;
    unsigned* cnt  = (unsigned*)(base + CNT_OFF);
    unsigned* part = (unsigned*)(base + PART_OFF);
    int i = chunk * 256 + t;
    unsigned v = cnt[i];
    __shared__ unsigned s[256];
    s[t] = v; __syncthreads();
#pragma unroll
    for (int dd = 1; dd < 256; dd <<= 1) {
        unsigned x = (t >= dd) ? s[t - dd] : 0u;
        __syncthreads();
        s[t] += x;
        __syncthreads();
    }
    cnt[i] = s[t] - v;
    if (t == 255) part[chunk] = s[255];
}

// K2b: one block per batch — in-place exclusive scan of the 3125 partials.
__global__ __launch_bounds__(256) void scan_partials_kernel(char* __restrict__ ws) {
    int lb = blockIdx.x, t = threadIdx.x;
    unsigned* p = (unsigned*)(ws + (size_t)lb * BSTRIDE + PART_OFF);
    const int per = (kNCHUNK + 255) / 256;    // 13
    int lo = t * per, hi = lo + per; if (hi > kNCHUNK) hi = kNCHUNK;
    unsigned sum = 0;
    for (int i = lo; i < hi; ++i) sum += p[i];
    __shared__ unsigned s[256];
    s[t] = sum; __syncthreads();
    unsigned own = sum;
#pragma unroll
    for (int dd = 1; dd < 256; dd <<= 1) {
        unsigned x = (t >= dd) ? s[t - dd] : 0u;
        __syncthreads();
        s[t] += x;
        __syncthreads();
    }
    unsigned running = s[t] - own;
    for (int i = lo; i < hi; ++i) {
        unsigned tmp = p[i]; p[i] = running; running += tmp;
    }
}

// K2c: cnt[i] += chunk base -> global exclusive offsets (= scatter cursor).
__global__ __launch_bounds__(256) void scan_add_kernel(char* __restrict__ ws) {
    int blk = blockIdx.x, t = threadIdx.x;
    int lb = blk / kNCHUNK, chunk = blk - lb * kNCHUNK;
    char* base = ws + (size_t)lb * BSTRIDE;
    unsigned* cnt = (unsigned*)(base + CNT_OFF);
    const unsigned* part = (const unsigned*)(base + PART_OFF);
    cnt[chunk * 256 + t] += part[chunk];
}

// K3: scatter (pix<<12 | mask) into buckets. After: cnt[c] == END of bucket c.
__global__ __launch_bounds__(256) void scatter_kernel(
        const float* __restrict__ obs, char* __restrict__ ws,
        int b0, int nb, float rcpF) {
    int t = blockIdx.x * blockDim.x + threadIdx.x;
    if (t >= nb * kNPIX) return;
    int lb = t / kNPIX, pix = t - lb * kNPIX;
    const float* ob = obs + (size_t)(b0 + lb) * kNCH * kNPIX;
    unsigned cell, mask;
    if (!cellmask(ob, pix, rcpF, cell, mask, true)) return;
    char* base = ws + (size_t)lb * BSTRIDE;
    unsigned slot = atomicAdd((unsigned*)(base + CNT_OFF) + cell, 1u);
    ((unsigned*)(base + IDX_OFF))[slot] = ((unsigned)pix << 12) | mask;
}

// K3s: per cell — insertion-sort its bucket ascending (key order = pix order).
__global__ __launch_bounds__(256) void sort_kernel(char* __restrict__ ws, int nb) {
    int t = blockIdx.x * blockDim.x + threadIdx.x;
    if (t >= nb * kNCELL) return;
    int lb = t / kNCELL, c = t - lb * kNCELL;
    char* base = ws + (size_t)lb * BSTRIDE;
    const unsigned* cnt = (const unsigned*)(base + CNT_OFF);
    int lo = (c == 0) ? 0 : (int)cnt[c - 1];
    int hi = (int)cnt[c];
    unsigned* idx = (unsigned*)(base + IDX_OFF);
    for (int i = lo + 1; i < hi; ++i) {
        unsigned v = idx[i];
        int j = i - 1;
        while (j >= lo && idx[j] > v) { idx[j + 1] = idx[j]; --j; }
        idx[j + 1] = v;
    }
}

// K4: gather — per voxel: XLA-canonical f32 weights, f32 sequential
// accumulation in scatter order (corner-major itertools order, pixel
// ascending — XLA:CPU scatter iterates updates linearly).
__global__ __launch_bounds__(256) void gather_kernel(
        const float* __restrict__ obs, char* __restrict__ ws,
        int b0, int nb, float rcpF) {
    const int perb = 79 * 99 * 99;            // 774279
    int t = blockIdx.x * blockDim.x + threadIdx.x;
    if (t >= nb * perb) return;
    int lb = t / perb, r = t - lb * perb;
    int z = r / (99 * 99) + 1;
    int rem = r - (z - 1) * (99 * 99);
    int y = rem / 99 + 1;
    int x = rem - (y - 1) * 99 + 1;

    char* base = ws + (size_t)lb * BSTRIDE;
    const unsigned* cnt = (const unsigned*)(base + CNT_OFF);
    const unsigned* idx = (const unsigned*)(base + IDX_OFF);
    const float* ob = obs + (size_t)(b0 + lb) * kNCH * kNPIX;

    bool win = (z >= kZLO) && (z < kZHI);
    float xf = (float)x, yf = (float)y, zf = (float)z;

    float s0 = 0.0f;
    float ssem[kNSEM];
#pragma unroll
    for (int c = 0; c < kNSEM; ++c) ssem[c] = 0.0f;

#pragma unroll
    for (int cc = 0; cc < 8; ++cc) {          // (c0,c1,c2), c2 fastest = product order
        int c0 = (cc >> 2) & 1, c1 = (cc >> 1) & 1, c2 = cc & 1;
        unsigned cell = ((unsigned)((x - c0) * kVR + (y - c1))) * (unsigned)kNZ
                      + (unsigned)(z - c2);
        unsigned lo = (cell == 0u) ? 0u : cnt[cell - 1];
        unsigned hi = cnt[cell];
        for (unsigned k = lo; k < hi; ++k) {
            unsigned key = idx[k];
            int pix = (int)(key >> 12);
            int zi = pix / kW, xi = pix - zi * kW;
            float d = ob[3 * kNPIX + pix];
            float p0, p1, p2;
            geom_f(xi, zi, d, rcpF, p0, p1, p2);
            float w0 = 1.0f - fabsf(p0 - xf);
            float w1 = 1.0f - fabsf(p1 - yf);
            float w2 = 1.0f - fabsf(p2 - zf);
            float wt = nofuse_f((w0 * w1) * w2);   // ref assoc; no fma into add
            s0 += wt;
            if (win) {
                unsigned m = key & 0xFFFu;
#pragma unroll
                for (int c = 0; c < kNSEM; ++c)
                    if (m & (1u << c)) ssem[c] += wt;
            }
        }
    }

    float* col = (float*)(base + COL_OFF);
    int ij = y * kVR + x;
    float v0 = rintf(s0);                      // round half-to-even (f32)
    if (v0 != 0.0f) {
        atomicAdd(col + 1 * 10000 + ij, v0);            // exp (all z)
        if (win) atomicAdd(col + 0 * 10000 + ij, v0);   // map (window)
    }
    if (win) {
#pragma unroll
        for (int c = 0; c < kNSEM; ++c) {
            float vc = rintf(ssem[c]);
            if (vc != 0.0f) atomicAdd(col + (2 + c) * 10000 + ij, vc);
        }
    }
}

// K5: clip column sums into output. /5 -> *0.2f (same recip rewrite; equal
// bits for all integer counts 0..5).
__global__ __launch_bounds__(256) void finalize_kernel(
        const char* __restrict__ ws, float* __restrict__ out, int b0, int nb) {
    int t = blockIdx.x * blockDim.x + threadIdx.x;
    if (t >= nb * 14 * 10000) return;
    int lb = t / 140000, r = t - lb * 140000;
    int m = r / 10000, ij = r - m * 10000;
    int b = b0 + lb;
    const float* col = (const float*)(ws + (size_t)lb * BSTRIDE + COL_OFF);
    float v = col[m * 10000 + ij];
    if (m == 0)      out[b * 10000 + ij]              = fminf(fmaxf(v, 0.0f), 1.0f);
    else if (m == 1) out[kB * 10000 + b * 10000 + ij] = fminf(fmaxf(v, 0.0f), 1.0f);
    else             out[2 * kB * 10000 + (b * kNSEM + (m - 2)) * 10000 + ij]
                        = fminf(fmaxf(v * 0.2f, 0.0f), 1.0f);
}

// ---------------- host ----------------
static void run_exact(const float* obs, float* out, char* ws,
                      int b0, int nb, float rcpF, hipStream_t stream) {
    for (int lb = 0; lb < nb; ++lb) {
        hipMemsetAsync(ws + (size_t)lb * BSTRIDE + CNT_OFF, 0, (size_t)kNCELL * 4, stream);
        hipMemsetAsync(ws + (size_t)lb * BSTRIDE + COL_OFF, 0, (size_t)14 * 10000 * 4, stream);
    }
    int n1 = nb * kNPIX;
    build_kernel<<<(n1 + 255) / 256, 256, 0, stream>>>(obs, ws, b0, nb, rcpF);
    scan_block_kernel<<<nb * kNCHUNK, 256, 0, stream>>>(ws);
    scan_partials_kernel<<<nb, 256, 0, stream>>>(ws);
    scan_add_kernel<<<nb * kNCHUNK, 256, 0, stream>>>(ws);
    scatter_kernel<<<(n1 + 255) / 256, 256, 0, stream>>>(obs, ws, b0, nb, rcpF);
    int n2 = nb * kNCELL;
    sort_kernel<<<(n2 + 255) / 256, 256, 0, stream>>>(ws, nb);
    int n3 = nb * 79 * 99 * 99;
    gather_kernel<<<(n3 + 255) / 256, 256, 0, stream>>>(obs, ws, b0, nb, rcpF);
    int n4 = nb * 14 * 10000;
    finalize_kernel<<<(n4 + 255) / 256, 256, 0, stream>>>(ws, out, b0, nb);
}

extern "C" void kernel_launch(void* const* d_in, const int* in_sizes, int n_in,
                              void* d_out, int out_size, void* d_ws, size_t ws_size,
                              hipStream_t stream) {
    const float* obs = (const float*)d_in[0];
    float* out = (float*)d_out;
    char* ws = (char*)d_ws;

    // F_CAM in f64 as numpy (deg2rad(x) = x*(pi/180)), demoted to the f32
    // graph literal; XLA folds its reciprocal at compile time in f32.
    double rad = (79.0 / 2.0) * (M_PI / 180.0);
    float f_cam = (float)(640.0 / 2.0 / tan(rad));
    float rcpF  = 1.0f / f_cam;

    if (ws_size >= (size_t)kB * BSTRIDE) {
        run_exact(obs, out, ws, 0, kB, rcpF, stream);         // 20 MB: 4-batch parallel
    } else {
        for (int b = 0; b < kB; ++b)                           // 5 MB: sequential
            run_exact(obs, out, ws, b, 1, rcpF, stream);
    }
}

// Round 13
// 405.135 us; speedup vs baseline: 1.3120x; 1.3120x over previous
//
#include <hip/hip_runtime.h>
#include <math.h>

// Problem constants
constexpr int kB    = 4;
constexpr int kNSEM = 12;
constexpr int kH    = 480;
constexpr int kW    = 640;
constexpr int kNPIX = kH * kW;           // 307200
constexpr int kNCH  = 16;                // rgb(3) + depth(1) + sem(12)
constexpr int kVR   = 100;
constexpr int kNZ   = 80;
constexpr int kZLO  = 13;                // agent window [13,25)
constexpr int kZHI  = 25;
constexpr int kNCELL  = kVR * kVR * kNZ; // 800000 floor-cells
constexpr int kNCHUNK = kNCELL / 256;    // 3125

// ---- per-batch ws layout (templated on WIDE entries) ----
// WIDE:  entry = uint2{pix<<12|mask, f32 depth bits} (8B) — gather never
//        touches obs (kills the random-read over-fetch).
// !WIDE: entry = u32 pix<<12|mask (4B) — byte-identical to the R12 layout
//        (proven pass) for small-ws fallback.
template <bool WIDE> struct Layout {
    static constexpr size_t CNT_OFF  = 0;                                  // 800000 u32
    static constexpr size_t ENT_OFF  = (size_t)kNCELL * 4;                 // entries
    static constexpr size_t ENT_SZ   = WIDE ? 8 : 4;
    static constexpr size_t PART_OFF = ENT_OFF + (size_t)kNPIX * ENT_SZ;   // 3125 u32
    static constexpr size_t COL_OFF  = PART_OFF + 12544;                   // 14x10000 f32
    static constexpr size_t BSTRIDE  = COL_OFF + (size_t)14 * 10000 * 4;
};
// WIDE: 6,230,144 B/batch.  narrow: 5,001,344 B/batch (== R12).

// Block hipcc contraction of the weight product into the accumulate add
// (XLA's scatter adds are separately rounded).
__device__ __forceinline__ float nofuse_f(float x) {
    asm volatile("" : "+v"(x));
    return x;
}

// XLA-jit canonical geometry — FROZEN (bit-exact vs golden, R12):
//   p0 = fma(tx, rcpF, 250) * 0.2f
//   p1 = d * 0.2f
//   p2 = fma(fma(tz, rcpF, 88), 0.2f, 8)
__device__ __forceinline__ void geom_f(int xi, int zi, float d, float rcpF,
                                       float& p0, float& p1, float& p2) {
    float tx  = ((float)xi - 319.5f) * d;
    float tz  = (239.5f - (float)zi) * d;
    float x_w = fmaf(tx, rcpF, 250.0f);
    float z_w = fmaf(tz, rcpF, 88.0f);
    p0 = x_w * 0.2f;
    p1 = d   * 0.2f;
    p2 = fmaf(z_w, 0.2f, 8.0f);
}

__device__ __forceinline__ bool cellmask(const float* __restrict__ ob, int pix,
                                         float rcpF, unsigned& cell,
                                         unsigned& mask, float& dout,
                                         bool want_mask) {
    int zi = pix / kW, xi = pix - zi * kW;
    float d = ob[3 * kNPIX + pix];
    dout = d;
    float p0, p1, p2;
    geom_f(xi, zi, d, rcpF, p0, p1, p2);
    int fx = (int)floorf(p0), fy = (int)floorf(p1), fz = (int)floorf(p2);
    if (fx < 0 || fx >= kVR || fy < 0 || fy >= kVR || fz < 0 || fz >= kNZ)
        return false;
    cell = ((unsigned)(fx * kVR + fy)) * (unsigned)kNZ + (unsigned)fz;
    mask = 0;
    if (want_mask) {
#pragma unroll
        for (int c = 0; c < kNSEM; ++c)
            if (ob[(4 + c) * kNPIX + pix] != 0.0f) mask |= (1u << c);
    }
    return true;
}

// K1: count pixels per floor cell (layout-independent: CNT at offset 0).
template <bool WIDE>
__global__ __launch_bounds__(256) void build_kernel(
        const float* __restrict__ obs, char* __restrict__ ws,
        int b0, int nb, float rcpF) {
    using L = Layout<WIDE>;
    int t = blockIdx.x * blockDim.x + threadIdx.x;
    if (t >= nb * kNPIX) return;
    int lb = t / kNPIX, pix = t - lb * kNPIX;
    const float* ob = obs + (size_t)(b0 + lb) * kNCH * kNPIX;
    unsigned cell, mask; float d;
    if (cellmask(ob, pix, rcpF, cell, mask, d, false))
        atomicAdd((unsigned*)(ws + (size_t)lb * L::BSTRIDE + L::CNT_OFF) + cell, 1u);
}

// K2a: per 256-cell chunk — in-place chunk-exclusive scan; chunk total -> part.
template <bool WIDE>
__global__ __launch_bounds__(256) void scan_block_kernel(char* __restrict__ ws) {
    using L = Layout<WIDE>;
    int blk = blockIdx.x, t = threadIdx.x;
    int lb = blk / kNCHUNK, chunk = blk - lb * kNCHUNK;
    char* base = ws + (size_t)lb * L::BSTRIDE;
    unsigned* cnt  = (unsigned*)(base + L::CNT_OFF);
    unsigned* part = (unsigned*)(base + L::PART_OFF);
    int i = chunk * 256 + t;
    unsigned v = cnt[i];
    __shared__ unsigned s[256];
    s[t] = v; __syncthreads();
#pragma unroll
    for (int dd = 1; dd < 256; dd <<= 1) {
        unsigned x = (t >= dd) ? s[t - dd] : 0u;
        __syncthreads();
        s[t] += x;
        __syncthreads();
    }
    cnt[i] = s[t] - v;
    if (t == 255) part[chunk] = s[255];
}

// K2b: one block per batch — in-place exclusive scan of the 3125 partials.
template <bool WIDE>
__global__ __launch_bounds__(256) void scan_partials_kernel(char* __restrict__ ws) {
    using L = Layout<WIDE>;
    int lb = blockIdx.x, t = threadIdx.x;
    unsigned* p = (unsigned*)(ws + (size_t)lb * L::BSTRIDE + L::PART_OFF);
    const int per = (kNCHUNK + 255) / 256;    // 13
    int lo = t * per, hi = lo + per; if (hi > kNCHUNK) hi = kNCHUNK;
    unsigned sum = 0;
    for (int i = lo; i < hi; ++i) sum += p[i];
    __shared__ unsigned s[256];
    s[t] = sum; __syncthreads();
    unsigned own = sum;
#pragma unroll
    for (int dd = 1; dd < 256; dd <<= 1) {
        unsigned x = (t >= dd) ? s[t - dd] : 0u;
        __syncthreads();
        s[t] += x;
        __syncthreads();
    }
    unsigned running = s[t] - own;
    for (int i = lo; i < hi; ++i) {
        unsigned tmp = p[i]; p[i] = running; running += tmp;
    }
}

// K2c: cnt[i] += chunk base -> global exclusive offsets (= scatter cursor).
template <bool WIDE>
__global__ __launch_bounds__(256) void scan_add_kernel(char* __restrict__ ws) {
    using L = Layout<WIDE>;
    int blk = blockIdx.x, t = threadIdx.x;
    int lb = blk / kNCHUNK, chunk = blk - lb * kNCHUNK;
    char* base = ws + (size_t)lb * L::BSTRIDE;
    unsigned* cnt = (unsigned*)(base + L::CNT_OFF);
    const unsigned* part = (const unsigned*)(base + L::PART_OFF);
    cnt[chunk * 256 + t] += part[chunk];
}

// K3: scatter entries into buckets. After: cnt[c] == END of bucket c.
template <bool WIDE>
__global__ __launch_bounds__(256) void scatter_kernel(
        const float* __restrict__ obs, char* __restrict__ ws,
        int b0, int nb, float rcpF) {
    using L = Layout<WIDE>;
    int t = blockIdx.x * blockDim.x + threadIdx.x;
    if (t >= nb * kNPIX) return;
    int lb = t / kNPIX, pix = t - lb * kNPIX;
    const float* ob = obs + (size_t)(b0 + lb) * kNCH * kNPIX;
    unsigned cell, mask; float d;
    if (!cellmask(ob, pix, rcpF, cell, mask, d, true)) return;
    char* base = ws + (size_t)lb * L::BSTRIDE;
    unsigned slot = atomicAdd((unsigned*)(base + L::CNT_OFF) + cell, 1u);
    unsigned key = ((unsigned)pix << 12) | mask;
    if (WIDE) {
        uint2 e; e.x = key; e.y = __float_as_uint(d);
        ((uint2*)(base + L::ENT_OFF))[slot] = e;
    } else {
        ((unsigned*)(base + L::ENT_OFF))[slot] = key;
    }
}

// K3s: per cell — insertion-sort its bucket ascending by key (= pix order).
template <bool WIDE>
__global__ __launch_bounds__(256) void sort_kernel(char* __restrict__ ws, int nb) {
    using L = Layout<WIDE>;
    int t = blockIdx.x * blockDim.x + threadIdx.x;
    if (t >= nb * kNCELL) return;
    int lb = t / kNCELL, c = t - lb * kNCELL;
    char* base = ws + (size_t)lb * L::BSTRIDE;
    const unsigned* cnt = (const unsigned*)(base + L::CNT_OFF);
    int lo = (c == 0) ? 0 : (int)cnt[c - 1];
    int hi = (int)cnt[c];
    if (WIDE) {
        uint2* ent = (uint2*)(base + L::ENT_OFF);
        for (int i = lo + 1; i < hi; ++i) {
            uint2 v = ent[i];
            int j = i - 1;
            while (j >= lo && ent[j].x > v.x) { ent[j + 1] = ent[j]; --j; }
            ent[j + 1] = v;
        }
    } else {
        unsigned* ent = (unsigned*)(base + L::ENT_OFF);
        for (int i = lo + 1; i < hi; ++i) {
            unsigned v = ent[i];
            int j = i - 1;
            while (j >= lo && ent[j] > v) { ent[j + 1] = ent[j]; --j; }
            ent[j + 1] = v;
        }
    }
}

// K4: gather — per voxel: frozen f32 weights, f32 sequential accumulation in
// scatter order (corner-major itertools order, pixel ascending).
// Thread mapping z-fastest: adjacent lanes scan adjacent bucket ranges
// (cell layout is z-fastest) -> coalesced entry reads, L2-resident.
template <bool WIDE>
__global__ __launch_bounds__(256) void gather_kernel(
        const float* __restrict__ obs, char* __restrict__ ws,
        int b0, int nb, float rcpF) {
    using L = Layout<WIDE>;
    const int perb = 99 * 99 * 79;            // 774279
    int t = blockIdx.x * blockDim.x + threadIdx.x;
    if (t >= nb * perb) return;
    int lb = t / perb, r = t - lb * perb;
    int x = r / (99 * 79) + 1;
    int rem = r - (x - 1) * (99 * 79);
    int y = rem / 79 + 1;
    int z = rem - (y - 1) * 79 + 1;

    char* base = ws + (size_t)lb * L::BSTRIDE;
    const unsigned* cnt = (const unsigned*)(base + L::CNT_OFF);
    const float* ob = obs + (size_t)(b0 + lb) * kNCH * kNPIX;

    bool win = (z >= kZLO) && (z < kZHI);
    float xf = (float)x, yf = (float)y, zf = (float)z;

    float s0 = 0.0f;
    float ssem[kNSEM];
#pragma unroll
    for (int c = 0; c < kNSEM; ++c) ssem[c] = 0.0f;

#pragma unroll
    for (int cc = 0; cc < 8; ++cc) {          // (c0,c1,c2), c2 fastest = product order
        int c0 = (cc >> 2) & 1, c1 = (cc >> 1) & 1, c2 = cc & 1;
        unsigned cell = ((unsigned)((x - c0) * kVR + (y - c1))) * (unsigned)kNZ
                      + (unsigned)(z - c2);
        unsigned lo = (cell == 0u) ? 0u : cnt[cell - 1];
        unsigned hi = cnt[cell];
        for (unsigned k = lo; k < hi; ++k) {
            unsigned key; float d;
            if (WIDE) {
                uint2 e = ((const uint2*)(base + L::ENT_OFF))[k];
                key = e.x; d = __uint_as_float(e.y);
            } else {
                key = ((const unsigned*)(base + L::ENT_OFF))[k];
                int pix = (int)(key >> 12);
                d = ob[3 * kNPIX + pix];
            }
            int pix = (int)(key >> 12);
            int zi = pix / kW, xi = pix - zi * kW;
            float p0, p1, p2;
            geom_f(xi, zi, d, rcpF, p0, p1, p2);
            float w0 = 1.0f - fabsf(p0 - xf);
            float w1 = 1.0f - fabsf(p1 - yf);
            float w2 = 1.0f - fabsf(p2 - zf);
            float wt = nofuse_f((w0 * w1) * w2);   // ref assoc; no fma into add
            s0 += wt;
            if (win) {
                unsigned m = key & 0xFFFu;
#pragma unroll
                for (int c = 0; c < kNSEM; ++c)
                    if (m & (1u << c)) ssem[c] += wt;
            }
        }
    }

    float* col = (float*)(base + L::COL_OFF);
    int ij = y * kVR + x;
    float v0 = rintf(s0);                      // round half-to-even (f32)
    if (v0 != 0.0f) {
        atomicAdd(col + 1 * 10000 + ij, v0);            // exp (all z)
        if (win) atomicAdd(col + 0 * 10000 + ij, v0);   // map (window)
    }
    if (win) {
#pragma unroll
        for (int c = 0; c < kNSEM; ++c) {
            float vc = rintf(ssem[c]);
            if (vc != 0.0f) atomicAdd(col + (2 + c) * 10000 + ij, vc);
        }
    }
}

// K5: clip column sums into output. /5 -> *0.2f (frozen).
template <bool WIDE>
__global__ __launch_bounds__(256) void finalize_kernel(
        const char* __restrict__ ws, float* __restrict__ out, int b0, int nb) {
    using L = Layout<WIDE>;
    int t = blockIdx.x * blockDim.x + threadIdx.x;
    if (t >= nb * 14 * 10000) return;
    int lb = t / 140000, r = t - lb * 140000;
    int m = r / 10000, ij = r - m * 10000;
    int b = b0 + lb;
    const float* col = (const float*)(ws + (size_t)lb * L::BSTRIDE + L::COL_OFF);
    float v = col[m * 10000 + ij];
    if (m == 0)      out[b * 10000 + ij]              = fminf(fmaxf(v, 0.0f), 1.0f);
    else if (m == 1) out[kB * 10000 + b * 10000 + ij] = fminf(fmaxf(v, 0.0f), 1.0f);
    else             out[2 * kB * 10000 + (b * kNSEM + (m - 2)) * 10000 + ij]
                        = fminf(fmaxf(v * 0.2f, 0.0f), 1.0f);
}

// ---------------- host ----------------
template <bool WIDE>
static void run_exact(const float* obs, float* out, char* ws,
                      int b0, int nb, float rcpF, hipStream_t stream) {
    using L = Layout<WIDE>;
    for (int lb = 0; lb < nb; ++lb) {
        hipMemsetAsync(ws + (size_t)lb * L::BSTRIDE + L::CNT_OFF, 0, (size_t)kNCELL * 4, stream);
        hipMemsetAsync(ws + (size_t)lb * L::BSTRIDE + L::COL_OFF, 0, (size_t)14 * 10000 * 4, stream);
    }
    int n1 = nb * kNPIX;
    build_kernel<WIDE><<<(n1 + 255) / 256, 256, 0, stream>>>(obs, ws, b0, nb, rcpF);
    scan_block_kernel<WIDE><<<nb * kNCHUNK, 256, 0, stream>>>(ws);
    scan_partials_kernel<WIDE><<<nb, 256, 0, stream>>>(ws);
    scan_add_kernel<WIDE><<<nb * kNCHUNK, 256, 0, stream>>>(ws);
    scatter_kernel<WIDE><<<(n1 + 255) / 256, 256, 0, stream>>>(obs, ws, b0, nb, rcpF);
    int n2 = nb * kNCELL;
    sort_kernel<WIDE><<<(n2 + 255) / 256, 256, 0, stream>>>(ws, nb);
    int n3 = nb * 99 * 99 * 79;
    gather_kernel<WIDE><<<(n3 + 255) / 256, 256, 0, stream>>>(obs, ws, b0, nb, rcpF);
    int n4 = nb * 14 * 10000;
    finalize_kernel<WIDE><<<(n4 + 255) / 256, 256, 0, stream>>>(ws, out, b0, nb);
}

extern "C" void kernel_launch(void* const* d_in, const int* in_sizes, int n_in,
                              void* d_out, int out_size, void* d_ws, size_t ws_size,
                              hipStream_t stream) {
    const float* obs = (const float*)d_in[0];
    float* out = (float*)d_out;
    char* ws = (char*)d_ws;

    // F_CAM in f64 as numpy (deg2rad(x) = x*(pi/180)), demoted to the f32
    // graph literal; reciprocal folded in f32 (frozen, bit-exact R12).
    double rad = (79.0 / 2.0) * (M_PI / 180.0);
    float f_cam = (float)(640.0 / 2.0 / tan(rad));
    float rcpF  = 1.0f / f_cam;

    if (ws_size >= (size_t)kB * Layout<true>::BSTRIDE) {
        run_exact<true>(obs, out, ws, 0, kB, rcpF, stream);     // 24.9 MB: parallel wide
    } else if (ws_size >= Layout<true>::BSTRIDE) {
        for (int b = 0; b < kB; ++b)                             // 6.23 MB: sequential wide
            run_exact<true>(obs, out, ws, b, 1, rcpF, stream);
    } else {
        for (int b = 0; b < kB; ++b)                             // 5.0 MB: R12-identical
            run_exact<false>(obs, out, ws, b, 1, rcpF, stream);
    }
}